// Round 13
// baseline (262.148 us; speedup 1.0000x reference)
//
#include <hip/hip_runtime.h>
#include <hip/hip_fp16.h>
#include <math.h>

#define F_IN 128
#define HID 64
#define HID2 32
#define EPS_BN 1e-5f
#define BW 128          // nodes per bucket
#define NBMAX 1024      // padded bucket count (actual NB = 782)
#define CAP 2560        // max edges per bucket (mean ~2046, +11 sigma)
#define CH 8192         // edges per partition workgroup

typedef _Float16 f16x8 __attribute__((ext_vector_type(8)));
typedef float f32x4 __attribute__((ext_vector_type(4)));

// ---------------- phase A: chunk counting-sort into bucket regions (1024 thr) ----------------
__global__ __launch_bounds__(1024) void partition_kernel(const int* __restrict__ src, const int* __restrict__ dst,
                                                         int E, int* __restrict__ gcursor,
                                                         unsigned* __restrict__ ebuf) {
    __shared__ int hist[NBMAX];
    __shared__ int start[NBMAX];
    __shared__ int cur[NBMAX];
    __shared__ int gb[NBMAX];
    __shared__ int sc[1024];
    __shared__ unsigned buf[CH];  // 32 KB
    int tid = threadIdx.x;
    int e0 = blockIdx.x * CH;
    hist[tid] = 0;
    __syncthreads();
#pragma unroll
    for (int it = 0; it < CH / 1024; it++) {
        int e = e0 + tid + it * 1024;
        if (e < E) atomicAdd(&hist[dst[e] >> 7], 1);
    }
    __syncthreads();
    int v = hist[tid];
    sc[tid] = v;
    __syncthreads();
    for (int off = 1; off < 1024; off <<= 1) {
        int t = (tid >= off) ? sc[tid - off] : 0;
        __syncthreads();
        sc[tid] += t;
        __syncthreads();
    }
    int ex = sc[tid] - v;  // exclusive prefix over buckets
    start[tid] = ex;
    cur[tid] = ex;
    gb[tid] = v ? atomicAdd(&gcursor[tid], v) : 0;   // reserve run in bucket region
    __syncthreads();
#pragma unroll
    for (int it = 0; it < CH / 1024; it++) {
        int e = e0 + tid + it * 1024;
        if (e < E) {
            int d = dst[e], s = src[e];
            int p = atomicAdd(&cur[d >> 7], 1);
            buf[p] = ((unsigned)(d & (BW - 1)) << 17) | (unsigned)s;  // src < 2^17
        }
    }
    __syncthreads();
    // write phase: 256 quad-groups x 4 buckets each
    int grp = tid >> 2, sub = tid & 3;
    for (int b = grp; b < NBMAX; b += 256) {
        int len = hist[b];
        if (!len) continue;
        int st = start[b];
        unsigned* dp = ebuf + (size_t)b * CAP + gb[b];
        for (int i = sub; i < len; i += 4) dp[i] = buf[st + i];
    }
}

// ---------------- phase B: per-bucket local sort; emits ns/ne/dinv and csr (in-place) ----------------
__global__ __launch_bounds__(256) void localsort_kernel(unsigned* __restrict__ ebuf, const int* __restrict__ gcursor,
                                                        int* __restrict__ ns, int* __restrict__ ne,
                                                        float* __restrict__ dinv, int n) {
    __shared__ unsigned lbuf[CAP];
    __shared__ int lhist[BW];
    __shared__ int lcur[BW];
    __shared__ int stmp[256];
    int b = blockIdx.x;
    int tid = threadIdx.x;
    int base = b * CAP;
    int len = gcursor[b];
    int node0 = b * BW;
    int nn = min(BW, n - node0);
    if (tid < BW) lhist[tid] = 0;
    __syncthreads();
    for (int k = tid; k < len; k += 256) {
        unsigned u = ebuf[base + k];
        lbuf[k] = u;
        atomicAdd(&lhist[u >> 17], 1);
    }
    __syncthreads();
    int v = (tid < BW) ? lhist[tid] : 0;
    stmp[tid] = v;
    __syncthreads();
    for (int off = 1; off < 256; off <<= 1) {
        int t = (tid >= off) ? stmp[tid - off] : 0;
        __syncthreads();
        stmp[tid] += t;
        __syncthreads();
    }
    int ex = stmp[tid] - v;  // exclusive within bucket
    if (tid < BW) lcur[tid] = ex;
    if (tid < nn) {
        ns[node0 + tid] = base + ex;
        ne[node0 + tid] = base + ex + v;
        dinv[node0 + tid] = rsqrtf((float)(v + 1));   // +1 self-loop
    }
    __syncthreads();
    for (int k = tid; k < len; k += 256) {
        unsigned u = lbuf[k];
        int p = atomicAdd(&lcur[u >> 17], 1);
        ebuf[base + p] = u & 0x1FFFFu;               // store global src id
    }
}

// ---------------- fold BN(eval)+bias into per-column scale/shift ----------------
__global__ void constprep_kernel(const float* g1, const float* be1, const float* rm1, const float* rv1, const float* b1,
                                 const float* g2, const float* be2, const float* rm2, const float* rv2, const float* b2,
                                 float* A1, float* B1, float* A2, float* B2) {
    int t = threadIdx.x;
    if (t < HID)  { float s = g1[t] * rsqrtf(rv1[t] + EPS_BN); A1[t] = s; B1[t] = (b1[t] - rm1[t]) * s + be1[t]; }
    if (t < HID2) { float s = g2[t] * rsqrtf(rv2[t] + EPS_BN); A2[t] = s; B2[t] = (b2[t] - rm2[t]) * s + be2[t]; }
}

// ---------------- GEMM1 (MFMA fp16): ht1 = fp16( (x @ W1) * dinv[row] ) ----------------
__global__ __launch_bounds__(256) void gemm1_kernel(const float* __restrict__ x, const float* __restrict__ W1,
                                                    const float* __restrict__ dinv, __half* __restrict__ ht1,
                                                    int n, int nwaves_tot) {
    __shared__ float wlds[F_IN * HID];   // 32 KB, [k][col]
    int tid = threadIdx.x;
    {
        const float4* wv = (const float4*)W1;
        float4* wl = (float4*)wlds;
#pragma unroll
        for (int i = 0; i < F_IN * HID / 4 / 256; i++) wl[tid + 256 * i] = wv[tid + 256 * i];
    }
    __syncthreads();
    int lane = tid & 63;
    int l15 = lane & 15, lg = lane >> 4;
    f16x8 bf[4][4];
#pragma unroll
    for (int ks = 0; ks < 4; ks++) {
#pragma unroll
        for (int ct = 0; ct < 4; ct++) {
            int kb = ks * 32 + lg * 8;
            int col = ct * 16 + l15;
            f16x8 b;
#pragma unroll
            for (int e = 0; e < 8; e++) b[e] = (_Float16)wlds[(kb + e) * HID + col];
            bf[ks][ct] = b;
        }
    }
    int gw = blockIdx.x * 4 + (tid >> 6);   // global wave id
    int nrt = (n + 15) >> 4;                // row-tiles of 16
    for (int rt = gw; rt < nrt; rt += nwaves_tot) {
        int arow = rt * 16 + l15;
        const float* xr = x + (size_t)min(arow, n - 1) * F_IN;
        f32x4 acc[4];
#pragma unroll
        for (int ct = 0; ct < 4; ct++) acc[ct] = (f32x4){0.f, 0.f, 0.f, 0.f};
#pragma unroll
        for (int ks = 0; ks < 4; ks++) {
            float4 xa = *(const float4*)(xr + ks * 32 + lg * 8);
            float4 xb = *(const float4*)(xr + ks * 32 + lg * 8 + 4);
            f16x8 a;
            a[0] = (_Float16)xa.x; a[1] = (_Float16)xa.y; a[2] = (_Float16)xa.z; a[3] = (_Float16)xa.w;
            a[4] = (_Float16)xb.x; a[5] = (_Float16)xb.y; a[6] = (_Float16)xb.z; a[7] = (_Float16)xb.w;
#pragma unroll
            for (int ct = 0; ct < 4; ct++)
                acc[ct] = __builtin_amdgcn_mfma_f32_16x16x32_f16(a, bf[ks][ct], acc[ct], 0, 0, 0);
        }
        int rbase = rt * 16 + lg * 4;
#pragma unroll
        for (int reg = 0; reg < 4; reg++) {
            int row = rbase + reg;
            if (row < n) {
                float d = dinv[row];
                _Float16* dp = (_Float16*)ht1 + (size_t)row * HID + l15;
#pragma unroll
                for (int ct = 0; ct < 4; ct++)
                    dp[ct * 16] = (_Float16)(acc[ct][reg] * d);
            }
        }
    }
}

// ---------------- GEMM2: ht2 = fp16( (h1p @ W2) * dinv[row] ) ----------------
#define XP2 68
__global__ __launch_bounds__(256) void gemm2_kernel(const float* __restrict__ h1p, const float* __restrict__ W2,
                                                    const float* __restrict__ dinv, __half* __restrict__ ht2,
                                                    int n) {
    __shared__ float wlds[HID * HID2];   // 8 KB, [k][col]
    __shared__ float xlds[64 * XP2];     // 17.4 KB
    int tid = threadIdx.x;
    {
        const float4* wv = (const float4*)W2;
        float4* wl = (float4*)wlds;
#pragma unroll
        for (int i = 0; i < HID * HID2 / 4 / 256; i++) wl[tid + 256 * i] = wv[tid + 256 * i];
    }
    int row0 = blockIdx.x * 64;
    {
        const float4* xv = (const float4*)(h1p + (size_t)row0 * HID);
        int lim = (n - row0) * (HID / 4);
#pragma unroll
        for (int i = 0; i < 4; i++) {
            int f = tid + 256 * i;
            float4 v = make_float4(0.f, 0.f, 0.f, 0.f);
            if (f < lim) v = xv[f];
            int r = f >> 4, kp = (f & 15) * 4;
            *(float4*)&xlds[r * XP2 + kp] = v;
        }
    }
    __syncthreads();
    int col4 = (tid & 7) * 4;
    int rowg = tid >> 3;
    float acc[2][4];
#pragma unroll
    for (int r = 0; r < 2; r++)
#pragma unroll
        for (int c = 0; c < 4; c++) acc[r][c] = 0.f;
#pragma unroll 4
    for (int k = 0; k < HID; k += 4) {
        float4 wb[4];
#pragma unroll
        for (int j = 0; j < 4; j++) wb[j] = *(const float4*)&wlds[(k + j) * HID2 + col4];
#pragma unroll
        for (int r = 0; r < 2; r++) {
            float4 xa = *(const float4*)&xlds[(rowg * 2 + r) * XP2 + k];
            acc[r][0] = fmaf(xa.x, wb[0].x, acc[r][0]); acc[r][1] = fmaf(xa.x, wb[0].y, acc[r][1]);
            acc[r][2] = fmaf(xa.x, wb[0].z, acc[r][2]); acc[r][3] = fmaf(xa.x, wb[0].w, acc[r][3]);
            acc[r][0] = fmaf(xa.y, wb[1].x, acc[r][0]); acc[r][1] = fmaf(xa.y, wb[1].y, acc[r][1]);
            acc[r][2] = fmaf(xa.y, wb[1].z, acc[r][2]); acc[r][3] = fmaf(xa.y, wb[1].w, acc[r][3]);
            acc[r][0] = fmaf(xa.z, wb[2].x, acc[r][0]); acc[r][1] = fmaf(xa.z, wb[2].y, acc[r][1]);
            acc[r][2] = fmaf(xa.z, wb[2].z, acc[r][2]); acc[r][3] = fmaf(xa.z, wb[2].w, acc[r][3]);
            acc[r][0] = fmaf(xa.w, wb[3].x, acc[r][0]); acc[r][1] = fmaf(xa.w, wb[3].y, acc[r][1]);
            acc[r][2] = fmaf(xa.w, wb[3].z, acc[r][2]); acc[r][3] = fmaf(xa.w, wb[3].w, acc[r][3]);
        }
    }
    int rbase = row0 + rowg * 2;
#pragma unroll
    for (int r = 0; r < 2; r++) {
        int row = rbase + r;
        if (row < n) {
            float d = dinv[row];
            __half2 h0, h1;
            h0.x = __float2half(acc[r][0] * d); h0.y = __float2half(acc[r][1] * d);
            h1.x = __float2half(acc[r][2] * d); h1.y = __float2half(acc[r][3] * d);
            __half2* dp = (__half2*)(ht2 + (size_t)row * HID2 + col4);
            dp[0] = h0; dp[1] = h1;
        }
    }
}

// ---------------- agg1: wave=node, lane=column, scalar (SGPR) edge indices ----------------
__global__ __launch_bounds__(256) void agg1_kernel(const __half* __restrict__ ht1, const int* __restrict__ ns,
                                                   const int* __restrict__ ne, const int* __restrict__ csr,
                                                   const float* __restrict__ dinv,
                                                   const float* __restrict__ A1, const float* __restrict__ B1,
                                                   float* __restrict__ h1p, int n) {
    int node = (blockIdx.x * blockDim.x + threadIdx.x) >> 6;
    node = __builtin_amdgcn_readfirstlane(node);   // uniform -> scalar loads for ns/ne/csr
    if (node >= n) return;
    int lane = threadIdx.x & 63;
    int s = __builtin_amdgcn_readfirstlane(ns[node]);
    int e_end = __builtin_amdgcn_readfirstlane(ne[node]);
    const _Float16* hp = (const _Float16*)ht1;
    float acc = (float)hp[(size_t)node * HID + lane];   // self-loop term
    int i = s;
    for (; i + 16 <= e_end; i += 16) {      // full blocks: unpredicated, uniform indices
        int idx[16];
#pragma unroll
        for (int j = 0; j < 16; j++) idx[j] = csr[i + j];
        float v[16];
#pragma unroll
        for (int j = 0; j < 16; j++) v[j] = (float)hp[(size_t)idx[j] * HID + lane];
        float t0 = ((v[0] + v[1]) + (v[2] + v[3])) + ((v[4] + v[5]) + (v[6] + v[7]));
        float t1 = ((v[8] + v[9]) + (v[10] + v[11])) + ((v[12] + v[13]) + (v[14] + v[15]));
        acc += t0 + t1;
    }
    if (i < e_end) {                        // one predicated tail block (clamped uniform idx)
        int idx[16];
        float m[16];
#pragma unroll
        for (int j = 0; j < 16; j++) {
            int e = i + j;
            bool vb = e < e_end;            // uniform
            idx[j] = csr[vb ? e : s];
            m[j] = vb ? 1.f : 0.f;
        }
#pragma unroll
        for (int j = 0; j < 16; j++)
            acc = fmaf((float)hp[(size_t)idx[j] * HID + lane], m[j], acc);
    }
    float d = dinv[node];
    float o = fmaxf(fmaf(acc * d, A1[lane], B1[lane]), 0.f);
    h1p[(size_t)node * HID + lane] = o;
}

// ---------------- agg2: wave=node, 2 rows/instr with scalar index pair + classifier + log_softmax ----------------
__global__ __launch_bounds__(256) void agg2_kernel(const __half* __restrict__ ht2, const int* __restrict__ ns,
                                                   const int* __restrict__ ne, const int* __restrict__ csr,
                                                   const float* __restrict__ dinv,
                                                   const float* __restrict__ A2, const float* __restrict__ B2,
                                                   const float* __restrict__ Wc, const float* __restrict__ bc,
                                                   float* __restrict__ out, int n) {
    int node = (blockIdx.x * blockDim.x + threadIdx.x) >> 6;
    node = __builtin_amdgcn_readfirstlane(node);
    if (node >= n) return;
    int lane = threadIdx.x & 63;
    int p = lane >> 5;          // row parity within pair
    int c = lane & 31;          // column
    int s = __builtin_amdgcn_readfirstlane(ns[node]);
    int e_end = __builtin_amdgcn_readfirstlane(ne[node]);
    const _Float16* hp = (const _Float16*)ht2;
    float acc = (p == 0) ? (float)hp[(size_t)node * HID2 + c] : 0.f;   // self once
    int i = s;
    for (; i + 16 <= e_end; i += 16) {
        int idx[8];
#pragma unroll
        for (int j = 0; j < 8; j++) {
            int ia = csr[i + 2 * j];        // scalar
            int ib = csr[i + 2 * j + 1];    // scalar
            idx[j] = p ? ib : ia;           // one cndmask
        }
        float v[8];
#pragma unroll
        for (int j = 0; j < 8; j++) v[j] = (float)hp[(size_t)idx[j] * HID2 + c];
        acc += ((v[0] + v[1]) + (v[2] + v[3])) + ((v[4] + v[5]) + (v[6] + v[7]));
    }
    if (i < e_end) {
#pragma unroll
        for (int j = 0; j < 8; j++) {
            int ea = i + 2 * j, eb = ea + 1;
            int ia = csr[(ea < e_end) ? ea : s];   // uniform clamped
            int ib = csr[(eb < e_end) ? eb : s];
            int idx = p ? ib : ia;
            int e = ea + p;                         // per-lane-half
            float f = (float)hp[(size_t)idx * HID2 + c];
            acc += (e < e_end) ? f : 0.f;
        }
    }
    acc += __shfl_xor(acc, 32);   // combine row parities; all lanes now full col sums
    float d = dinv[node];
    float v0 = fmaxf(fmaf(acc * d, A2[c], B2[c]), 0.f);
    float p0 = v0 * Wc[c * 2 + 0];
    float p1 = v0 * Wc[c * 2 + 1];
#pragma unroll
    for (int off = 16; off >= 1; off >>= 1) { p0 += __shfl_xor(p0, off); p1 += __shfl_xor(p1, off); }
    if (lane == 0) {
        float l0 = p0 + bc[0], l1 = p1 + bc[1];
        float m = fmaxf(l0, l1);
        float lse = m + logf(expf(l0 - m) + expf(l1 - m));
        float2 o; o.x = l0 - lse; o.y = l1 - lse;
        *(float2*)&out[(size_t)node * 2] = o;
    }
}

extern "C" void kernel_launch(void* const* d_in, const int* in_sizes, int n_in,
                              void* d_out, int out_size, void* d_ws, size_t ws_size,
                              hipStream_t stream) {
    const float* x   = (const float*)d_in[0];
    const int*   ei  = (const int*)d_in[1];     // harness converts int64 -> int32
    const float* W1  = (const float*)d_in[2];
    const float* b1  = (const float*)d_in[3];
    const float* W2  = (const float*)d_in[4];
    const float* b2  = (const float*)d_in[5];
    const float* g1  = (const float*)d_in[6];
    const float* be1 = (const float*)d_in[7];
    const float* rm1 = (const float*)d_in[8];
    const float* rv1 = (const float*)d_in[9];
    const float* g2  = (const float*)d_in[10];
    const float* be2 = (const float*)d_in[11];
    const float* rm2 = (const float*)d_in[12];
    const float* rv2 = (const float*)d_in[13];
    const float* Wc  = (const float*)d_in[14];
    const float* bc  = (const float*)d_in[15];
    float* out = (float*)d_out;

    int n = in_sizes[0] / F_IN;   // 100000
    int E = in_sizes[1] / 2;      // 1600000
    const int* srcv = ei;
    const int* dstv = ei + E;
    int NB = (n + BW - 1) / BW;   // 782

    char* ws = (char*)d_ws;
    size_t off = 0;
    auto alloc = [&](size_t bytes) -> char* {
        char* r = ws + off;
        off = (off + bytes + 511) & ~(size_t)511;
        return r;
    };
    int*      gcursor = (int*)alloc((size_t)NB * 4);
    int*      ns      = (int*)alloc((size_t)n * 4);
    int*      ne      = (int*)alloc((size_t)n * 4);
    float*    dinv    = (float*)alloc((size_t)n * 4);
    float*    A1 = (float*)alloc(HID * 4);
    float*    B1 = (float*)alloc(HID * 4);
    float*    A2 = (float*)alloc(HID2 * 4);
    float*    B2 = (float*)alloc(HID2 * 4);
    unsigned* ebuf = (unsigned*)alloc(((size_t)NB * CAP + 64) * 4);  // ~8 MB; becomes csr in-place
    __half*   ht1  = (__half*)alloc((size_t)n * HID * 2);     // fp16 gather table
    float*    h1p  = (float*)alloc((size_t)n * HID * 4);
    __half*   ht2  = ht1;  // ht1 dead after agg1; reuse region

    hipMemsetAsync(gcursor, 0, (size_t)NB * 4, stream);

    int nch = (E + CH - 1) / CH;  // 196
    partition_kernel<<<nch, 1024, 0, stream>>>(srcv, dstv, E, gcursor, ebuf);
    localsort_kernel<<<NB, 256, 0, stream>>>(ebuf, gcursor, ns, ne, dinv, n);
    constprep_kernel<<<1, 64, 0, stream>>>(g1, be1, rm1, rv1, b1, g2, be2, rm2, rv2, b2, A1, B1, A2, B2);

    int g1blocks = 512;           // 2048 waves
    gemm1_kernel<<<g1blocks, 256, 0, stream>>>(x, W1, dinv, ht1, n, g1blocks * 4);
    agg1_kernel<<<(n + 3) / 4, 256, 0, stream>>>(ht1, ns, ne, (const int*)ebuf, dinv, A1, B1, h1p, n);
    int ngb = (n + 63) / 64;      // 1563
    gemm2_kernel<<<ngb, 256, 0, stream>>>(h1p, W2, dinv, ht2, n);
    agg2_kernel<<<(n + 3) / 4, 256, 0, stream>>>(ht2, ns, ne, (const int*)ebuf, dinv, A2, B2, Wc, bc, out, n);
}

// Round 15
// 256.036 us; speedup vs baseline: 1.0239x; 1.0239x over previous
//
#include <hip/hip_runtime.h>
#include <hip/hip_fp16.h>
#include <math.h>

#define F_IN 128
#define HID 64
#define HID2 32
#define EPS_BN 1e-5f
#define BW 128          // nodes per bucket
#define NBMAX 1024      // padded bucket count (actual NB = 782)
#define CAP 2560        // max edges per bucket (mean ~2046, +11 sigma)
#define CH 8192         // edges per partition workgroup

typedef _Float16 f16x8 __attribute__((ext_vector_type(8)));
typedef float f32x4 __attribute__((ext_vector_type(4)));

// ---------------- phase A: chunk counting-sort into bucket regions (1024 thr) ----------------
__global__ __launch_bounds__(1024) void partition_kernel(const int* __restrict__ src, const int* __restrict__ dst,
                                                         int E, int* __restrict__ gcursor,
                                                         unsigned* __restrict__ ebuf) {
    __shared__ int hist[NBMAX];
    __shared__ int start[NBMAX];
    __shared__ int cur[NBMAX];
    __shared__ int gb[NBMAX];
    __shared__ int sc[1024];
    __shared__ unsigned buf[CH];  // 32 KB
    int tid = threadIdx.x;
    int e0 = blockIdx.x * CH;
    hist[tid] = 0;
    __syncthreads();
#pragma unroll
    for (int it = 0; it < CH / 1024; it++) {
        int e = e0 + tid + it * 1024;
        if (e < E) atomicAdd(&hist[dst[e] >> 7], 1);
    }
    __syncthreads();
    int v = hist[tid];
    sc[tid] = v;
    __syncthreads();
    for (int off = 1; off < 1024; off <<= 1) {
        int t = (tid >= off) ? sc[tid - off] : 0;
        __syncthreads();
        sc[tid] += t;
        __syncthreads();
    }
    int ex = sc[tid] - v;  // exclusive prefix over buckets
    start[tid] = ex;
    cur[tid] = ex;
    gb[tid] = v ? atomicAdd(&gcursor[tid], v) : 0;   // reserve run in bucket region
    __syncthreads();
#pragma unroll
    for (int it = 0; it < CH / 1024; it++) {
        int e = e0 + tid + it * 1024;
        if (e < E) {
            int d = dst[e], s = src[e];
            int p = atomicAdd(&cur[d >> 7], 1);
            buf[p] = ((unsigned)(d & (BW - 1)) << 17) | (unsigned)s;  // src < 2^17
        }
    }
    __syncthreads();
    // write phase: 256 quad-groups x 4 buckets each
    int grp = tid >> 2, sub = tid & 3;
    for (int b = grp; b < NBMAX; b += 256) {
        int len = hist[b];
        if (!len) continue;
        int st = start[b];
        unsigned* dp = ebuf + (size_t)b * CAP + gb[b];
        for (int i = sub; i < len; i += 4) dp[i] = buf[st + i];
    }
}

// ---------------- phase B: per-bucket local sort; emits ns/ne/dinv and csr (in-place) ----------------
__global__ __launch_bounds__(256) void localsort_kernel(unsigned* __restrict__ ebuf, const int* __restrict__ gcursor,
                                                        int* __restrict__ ns, int* __restrict__ ne,
                                                        float* __restrict__ dinv, int n) {
    __shared__ unsigned lbuf[CAP];
    __shared__ int lhist[BW];
    __shared__ int lcur[BW];
    __shared__ int stmp[256];
    int b = blockIdx.x;
    int tid = threadIdx.x;
    int base = b * CAP;
    int len = gcursor[b];
    int node0 = b * BW;
    int nn = min(BW, n - node0);
    if (tid < BW) lhist[tid] = 0;
    __syncthreads();
    for (int k = tid; k < len; k += 256) {
        unsigned u = ebuf[base + k];
        lbuf[k] = u;
        atomicAdd(&lhist[u >> 17], 1);
    }
    __syncthreads();
    int v = (tid < BW) ? lhist[tid] : 0;
    stmp[tid] = v;
    __syncthreads();
    for (int off = 1; off < 256; off <<= 1) {
        int t = (tid >= off) ? stmp[tid - off] : 0;
        __syncthreads();
        stmp[tid] += t;
        __syncthreads();
    }
    int ex = stmp[tid] - v;  // exclusive within bucket
    if (tid < BW) lcur[tid] = ex;
    if (tid < nn) {
        ns[node0 + tid] = base + ex;
        ne[node0 + tid] = base + ex + v;
        dinv[node0 + tid] = rsqrtf((float)(v + 1));   // +1 self-loop
    }
    __syncthreads();
    for (int k = tid; k < len; k += 256) {
        unsigned u = lbuf[k];
        int p = atomicAdd(&lcur[u >> 17], 1);
        ebuf[base + p] = u & 0x1FFFFu;               // store global src id
    }
}

// ---------------- fold BN(eval)+bias into per-column scale/shift ----------------
__global__ void constprep_kernel(const float* g1, const float* be1, const float* rm1, const float* rv1, const float* b1,
                                 const float* g2, const float* be2, const float* rm2, const float* rv2, const float* b2,
                                 float* A1, float* B1, float* A2, float* B2) {
    int t = threadIdx.x;
    if (t < HID)  { float s = g1[t] * rsqrtf(rv1[t] + EPS_BN); A1[t] = s; B1[t] = (b1[t] - rm1[t]) * s + be1[t]; }
    if (t < HID2) { float s = g2[t] * rsqrtf(rv2[t] + EPS_BN); A2[t] = s; B2[t] = (b2[t] - rm2[t]) * s + be2[t]; }
}

// ---------------- GEMM1 (MFMA fp16): ht1 = fp16( (x @ W1) * dinv[row] ) ----------------
__global__ __launch_bounds__(256) void gemm1_kernel(const float* __restrict__ x, const float* __restrict__ W1,
                                                    const float* __restrict__ dinv, __half* __restrict__ ht1,
                                                    int n, int nwaves_tot) {
    __shared__ float wlds[F_IN * HID];   // 32 KB, [k][col]
    int tid = threadIdx.x;
    {
        const float4* wv = (const float4*)W1;
        float4* wl = (float4*)wlds;
#pragma unroll
        for (int i = 0; i < F_IN * HID / 4 / 256; i++) wl[tid + 256 * i] = wv[tid + 256 * i];
    }
    __syncthreads();
    int lane = tid & 63;
    int l15 = lane & 15, lg = lane >> 4;
    f16x8 bf[4][4];
#pragma unroll
    for (int ks = 0; ks < 4; ks++) {
#pragma unroll
        for (int ct = 0; ct < 4; ct++) {
            int kb = ks * 32 + lg * 8;
            int col = ct * 16 + l15;
            f16x8 b;
#pragma unroll
            for (int e = 0; e < 8; e++) b[e] = (_Float16)wlds[(kb + e) * HID + col];
            bf[ks][ct] = b;
        }
    }
    int gw = blockIdx.x * 4 + (tid >> 6);   // global wave id
    int nrt = (n + 15) >> 4;                // row-tiles of 16
    for (int rt = gw; rt < nrt; rt += nwaves_tot) {
        int arow = rt * 16 + l15;
        const float* xr = x + (size_t)min(arow, n - 1) * F_IN;
        f32x4 acc[4];
#pragma unroll
        for (int ct = 0; ct < 4; ct++) acc[ct] = (f32x4){0.f, 0.f, 0.f, 0.f};
#pragma unroll
        for (int ks = 0; ks < 4; ks++) {
            float4 xa = *(const float4*)(xr + ks * 32 + lg * 8);
            float4 xb = *(const float4*)(xr + ks * 32 + lg * 8 + 4);
            f16x8 a;
            a[0] = (_Float16)xa.x; a[1] = (_Float16)xa.y; a[2] = (_Float16)xa.z; a[3] = (_Float16)xa.w;
            a[4] = (_Float16)xb.x; a[5] = (_Float16)xb.y; a[6] = (_Float16)xb.z; a[7] = (_Float16)xb.w;
#pragma unroll
            for (int ct = 0; ct < 4; ct++)
                acc[ct] = __builtin_amdgcn_mfma_f32_16x16x32_f16(a, bf[ks][ct], acc[ct], 0, 0, 0);
        }
        int rbase = rt * 16 + lg * 4;
#pragma unroll
        for (int reg = 0; reg < 4; reg++) {
            int row = rbase + reg;
            if (row < n) {
                float d = dinv[row];
                _Float16* dp = (_Float16*)ht1 + (size_t)row * HID + l15;
#pragma unroll
                for (int ct = 0; ct < 4; ct++)
                    dp[ct * 16] = (_Float16)(acc[ct][reg] * d);
            }
        }
    }
}

// ---------------- GEMM2: ht2 = fp16( (h1p @ W2) * dinv[row] ) ----------------
#define XP2 68
__global__ __launch_bounds__(256) void gemm2_kernel(const float* __restrict__ h1p, const float* __restrict__ W2,
                                                    const float* __restrict__ dinv, __half* __restrict__ ht2,
                                                    int n) {
    __shared__ float wlds[HID * HID2];   // 8 KB, [k][col]
    __shared__ float xlds[64 * XP2];     // 17.4 KB
    int tid = threadIdx.x;
    {
        const float4* wv = (const float4*)W2;
        float4* wl = (float4*)wlds;
#pragma unroll
        for (int i = 0; i < HID * HID2 / 4 / 256; i++) wl[tid + 256 * i] = wv[tid + 256 * i];
    }
    int row0 = blockIdx.x * 64;
    {
        const float4* xv = (const float4*)(h1p + (size_t)row0 * HID);
        int lim = (n - row0) * (HID / 4);
#pragma unroll
        for (int i = 0; i < 4; i++) {
            int f = tid + 256 * i;
            float4 v = make_float4(0.f, 0.f, 0.f, 0.f);
            if (f < lim) v = xv[f];
            int r = f >> 4, kp = (f & 15) * 4;
            *(float4*)&xlds[r * XP2 + kp] = v;
        }
    }
    __syncthreads();
    int col4 = (tid & 7) * 4;
    int rowg = tid >> 3;
    float acc[2][4];
#pragma unroll
    for (int r = 0; r < 2; r++)
#pragma unroll
        for (int c = 0; c < 4; c++) acc[r][c] = 0.f;
#pragma unroll 4
    for (int k = 0; k < HID; k += 4) {
        float4 wb[4];
#pragma unroll
        for (int j = 0; j < 4; j++) wb[j] = *(const float4*)&wlds[(k + j) * HID2 + col4];
#pragma unroll
        for (int r = 0; r < 2; r++) {
            float4 xa = *(const float4*)&xlds[(rowg * 2 + r) * XP2 + k];
            acc[r][0] = fmaf(xa.x, wb[0].x, acc[r][0]); acc[r][1] = fmaf(xa.x, wb[0].y, acc[r][1]);
            acc[r][2] = fmaf(xa.x, wb[0].z, acc[r][2]); acc[r][3] = fmaf(xa.x, wb[0].w, acc[r][3]);
            acc[r][0] = fmaf(xa.y, wb[1].x, acc[r][0]); acc[r][1] = fmaf(xa.y, wb[1].y, acc[r][1]);
            acc[r][2] = fmaf(xa.y, wb[1].z, acc[r][2]); acc[r][3] = fmaf(xa.y, wb[1].w, acc[r][3]);
            acc[r][0] = fmaf(xa.z, wb[2].x, acc[r][0]); acc[r][1] = fmaf(xa.z, wb[2].y, acc[r][1]);
            acc[r][2] = fmaf(xa.z, wb[2].z, acc[r][2]); acc[r][3] = fmaf(xa.z, wb[2].w, acc[r][3]);
            acc[r][0] = fmaf(xa.w, wb[3].x, acc[r][0]); acc[r][1] = fmaf(xa.w, wb[3].y, acc[r][1]);
            acc[r][2] = fmaf(xa.w, wb[3].z, acc[r][2]); acc[r][3] = fmaf(xa.w, wb[3].w, acc[r][3]);
        }
    }
    int rbase = row0 + rowg * 2;
#pragma unroll
    for (int r = 0; r < 2; r++) {
        int row = rbase + r;
        if (row < n) {
            float d = dinv[row];
            __half2 h0, h1;
            h0.x = __float2half(acc[r][0] * d); h0.y = __float2half(acc[r][1] * d);
            h1.x = __float2half(acc[r][2] * d); h1.y = __float2half(acc[r][3] * d);
            __half2* dp = (__half2*)(ht2 + (size_t)row * HID2 + col4);
            dp[0] = h0; dp[1] = h1;
        }
    }
}

// ---------------- agg1: wave=node, quad-groups, 4 rows per gather (8B/lane) ----------------
// q = lane>>4 edge slot, cp = lane&15 -> halves 4cp..4cp+3 (uint2 = 8B)
__global__ __launch_bounds__(256) void agg1_kernel(const __half* __restrict__ ht1, const int* __restrict__ ns,
                                                   const int* __restrict__ ne, const int* __restrict__ csr,
                                                   const float* __restrict__ dinv,
                                                   const float* __restrict__ A1, const float* __restrict__ B1,
                                                   float* __restrict__ h1p, int n) {
    int node = (blockIdx.x * blockDim.x + threadIdx.x) >> 6;
    if (node >= n) return;
    int lane = threadIdx.x & 63;
    int q = lane >> 4, cp = lane & 15;
    const uint2* htp = (const uint2*)ht1;   // row = 16 uint2 (128 B)
    int s = ns[node], e_end = ne[node];
    float a0 = 0.f, a1 = 0.f, a2 = 0.f, a3 = 0.f;
    if (q == 0) {   // self-loop term once
        uint2 u = htp[(size_t)node * 16 + cp];
        float2 f0 = __half22float2(*(__half2*)&u.x), f1 = __half22float2(*(__half2*)&u.y);
        a0 = f0.x; a1 = f0.y; a2 = f1.x; a3 = f1.y;
    }
    int i = s;
    for (; i + 16 <= e_end; i += 16) {    // 4 gathers, each covers 4 rows
        int i0 = csr[i + q], i1 = csr[i + 4 + q], i2 = csr[i + 8 + q], i3 = csr[i + 12 + q];
        uint2 u0 = htp[(size_t)i0 * 16 + cp];
        uint2 u1 = htp[(size_t)i1 * 16 + cp];
        uint2 u2 = htp[(size_t)i2 * 16 + cp];
        uint2 u3 = htp[(size_t)i3 * 16 + cp];
        float2 f;
        f = __half22float2(*(__half2*)&u0.x); a0 += f.x; a1 += f.y;
        f = __half22float2(*(__half2*)&u0.y); a2 += f.x; a3 += f.y;
        f = __half22float2(*(__half2*)&u1.x); a0 += f.x; a1 += f.y;
        f = __half22float2(*(__half2*)&u1.y); a2 += f.x; a3 += f.y;
        f = __half22float2(*(__half2*)&u2.x); a0 += f.x; a1 += f.y;
        f = __half22float2(*(__half2*)&u2.y); a2 += f.x; a3 += f.y;
        f = __half22float2(*(__half2*)&u3.x); a0 += f.x; a1 += f.y;
        f = __half22float2(*(__half2*)&u3.y); a2 += f.x; a3 += f.y;
    }
    if (i < e_end) {                       // predicated tail block
#pragma unroll
        for (int j = 0; j < 4; j++) {
            int e = i + 4 * j + q;
            bool vb = e < e_end;
            int idx = csr[vb ? e : s];
            uint2 u = htp[(size_t)idx * 16 + cp];
            float2 f0 = __half22float2(*(__half2*)&u.x), f1 = __half22float2(*(__half2*)&u.y);
            a0 += vb ? f0.x : 0.f; a1 += vb ? f0.y : 0.f;
            a2 += vb ? f1.x : 0.f; a3 += vb ? f1.y : 0.f;
        }
    }
    // reduce across the 4 quad groups (lane bits 4,5)
    a0 += __shfl_xor(a0, 16); a1 += __shfl_xor(a1, 16); a2 += __shfl_xor(a2, 16); a3 += __shfl_xor(a3, 16);
    a0 += __shfl_xor(a0, 32); a1 += __shfl_xor(a1, 32); a2 += __shfl_xor(a2, 32); a3 += __shfl_xor(a3, 32);
    if (q == 0) {
        float d = dinv[node];
        int c0 = cp * 4;
        float4 o;
        o.x = fmaxf(fmaf(a0 * d, A1[c0 + 0], B1[c0 + 0]), 0.f);
        o.y = fmaxf(fmaf(a1 * d, A1[c0 + 1], B1[c0 + 1]), 0.f);
        o.z = fmaxf(fmaf(a2 * d, A1[c0 + 2], B1[c0 + 2]), 0.f);
        o.w = fmaxf(fmaf(a3 * d, A1[c0 + 3], B1[c0 + 3]), 0.f);
        *(float4*)&h1p[(size_t)node * HID + c0] = o;
    }
}

// ---------------- agg2: wave=node, 8 rows per gather + classifier + log_softmax ----------------
// q = lane>>3 edge slot (0..7), cp = lane&7 -> halves 4cp..4cp+3 (uint2 = 8B; row = 8 uint2 = 64 B)
__global__ __launch_bounds__(256) void agg2_kernel(const __half* __restrict__ ht2, const int* __restrict__ ns,
                                                   const int* __restrict__ ne, const int* __restrict__ csr,
                                                   const float* __restrict__ dinv,
                                                   const float* __restrict__ A2, const float* __restrict__ B2,
                                                   const float* __restrict__ Wc, const float* __restrict__ bc,
                                                   float* __restrict__ out, int n) {
    int node = (blockIdx.x * blockDim.x + threadIdx.x) >> 6;
    if (node >= n) return;
    int lane = threadIdx.x & 63;
    int q = lane >> 3, cp = lane & 7;
    const uint2* htp = (const uint2*)ht2;   // row = 8 uint2 (64 B)
    int s = ns[node], e_end = ne[node];
    float a0 = 0.f, a1 = 0.f, a2 = 0.f, a3 = 0.f;
    if (q == 0) {
        uint2 u = htp[(size_t)node * 8 + cp];
        float2 f0 = __half22float2(*(__half2*)&u.x), f1 = __half22float2(*(__half2*)&u.y);
        a0 = f0.x; a1 = f0.y; a2 = f1.x; a3 = f1.y;
    }
    int i = s;
    for (; i + 16 <= e_end; i += 16) {    // 2 gathers, each covers 8 rows
        int i0 = csr[i + q], i1 = csr[i + 8 + q];
        uint2 u0 = htp[(size_t)i0 * 8 + cp];
        uint2 u1 = htp[(size_t)i1 * 8 + cp];
        float2 f;
        f = __half22float2(*(__half2*)&u0.x); a0 += f.x; a1 += f.y;
        f = __half22float2(*(__half2*)&u0.y); a2 += f.x; a3 += f.y;
        f = __half22float2(*(__half2*)&u1.x); a0 += f.x; a1 += f.y;
        f = __half22float2(*(__half2*)&u1.y); a2 += f.x; a3 += f.y;
    }
    if (i < e_end) {
#pragma unroll
        for (int j = 0; j < 2; j++) {
            int e = i + 8 * j + q;
            bool vb = e < e_end;
            int idx = csr[vb ? e : s];
            uint2 u = htp[(size_t)idx * 8 + cp];
            float2 f0 = __half22float2(*(__half2*)&u.x), f1 = __half22float2(*(__half2*)&u.y);
            a0 += vb ? f0.x : 0.f; a1 += vb ? f0.y : 0.f;
            a2 += vb ? f1.x : 0.f; a3 += vb ? f1.y : 0.f;
        }
    }
    // reduce across the 8 edge groups (lane bits 3,4,5)
    a0 += __shfl_xor(a0, 8);  a1 += __shfl_xor(a1, 8);  a2 += __shfl_xor(a2, 8);  a3 += __shfl_xor(a3, 8);
    a0 += __shfl_xor(a0, 16); a1 += __shfl_xor(a1, 16); a2 += __shfl_xor(a2, 16); a3 += __shfl_xor(a3, 16);
    a0 += __shfl_xor(a0, 32); a1 += __shfl_xor(a1, 32); a2 += __shfl_xor(a2, 32); a3 += __shfl_xor(a3, 32);
    // every lane holds full sums of cols 4cp..4cp+3
    float d = dinv[node];
    int c0 = cp * 4;
    float v0 = fmaxf(fmaf(a0 * d, A2[c0 + 0], B2[c0 + 0]), 0.f);
    float v1 = fmaxf(fmaf(a1 * d, A2[c0 + 1], B2[c0 + 1]), 0.f);
    float v2 = fmaxf(fmaf(a2 * d, A2[c0 + 2], B2[c0 + 2]), 0.f);
    float v3 = fmaxf(fmaf(a3 * d, A2[c0 + 3], B2[c0 + 3]), 0.f);
    float p0 = v0 * Wc[(c0 + 0) * 2] + v1 * Wc[(c0 + 1) * 2] + v2 * Wc[(c0 + 2) * 2] + v3 * Wc[(c0 + 3) * 2];
    float p1 = v0 * Wc[(c0 + 0) * 2 + 1] + v1 * Wc[(c0 + 1) * 2 + 1] + v2 * Wc[(c0 + 2) * 2 + 1] + v3 * Wc[(c0 + 3) * 2 + 1];
    // reduce over the 8 cp groups (lane bits 0,1,2)
#pragma unroll
    for (int off = 4; off >= 1; off >>= 1) { p0 += __shfl_xor(p0, off); p1 += __shfl_xor(p1, off); }
    if (lane == 0) {
        float l0 = p0 + bc[0], l1 = p1 + bc[1];
        float m = fmaxf(l0, l1);
        float lse = m + logf(expf(l0 - m) + expf(l1 - m));
        float2 o; o.x = l0 - lse; o.y = l1 - lse;
        *(float2*)&out[(size_t)node * 2] = o;
    }
}

extern "C" void kernel_launch(void* const* d_in, const int* in_sizes, int n_in,
                              void* d_out, int out_size, void* d_ws, size_t ws_size,
                              hipStream_t stream) {
    const float* x   = (const float*)d_in[0];
    const int*   ei  = (const int*)d_in[1];     // harness converts int64 -> int32
    const float* W1  = (const float*)d_in[2];
    const float* b1  = (const float*)d_in[3];
    const float* W2  = (const float*)d_in[4];
    const float* b2  = (const float*)d_in[5];
    const float* g1  = (const float*)d_in[6];
    const float* be1 = (const float*)d_in[7];
    const float* rm1 = (const float*)d_in[8];
    const float* rv1 = (const float*)d_in[9];
    const float* g2  = (const float*)d_in[10];
    const float* be2 = (const float*)d_in[11];
    const float* rm2 = (const float*)d_in[12];
    const float* rv2 = (const float*)d_in[13];
    const float* Wc  = (const float*)d_in[14];
    const float* bc  = (const float*)d_in[15];
    float* out = (float*)d_out;

    int n = in_sizes[0] / F_IN;   // 100000
    int E = in_sizes[1] / 2;      // 1600000
    const int* srcv = ei;
    const int* dstv = ei + E;
    int NB = (n + BW - 1) / BW;   // 782

    char* ws = (char*)d_ws;
    size_t off = 0;
    auto alloc = [&](size_t bytes) -> char* {
        char* r = ws + off;
        off = (off + bytes + 511) & ~(size_t)511;
        return r;
    };
    int*      gcursor = (int*)alloc((size_t)NB * 4);
    int*      ns      = (int*)alloc((size_t)n * 4);
    int*      ne      = (int*)alloc((size_t)n * 4);
    float*    dinv    = (float*)alloc((size_t)n * 4);
    float*    A1 = (float*)alloc(HID * 4);
    float*    B1 = (float*)alloc(HID * 4);
    float*    A2 = (float*)alloc(HID2 * 4);
    float*    B2 = (float*)alloc(HID2 * 4);
    unsigned* ebuf = (unsigned*)alloc(((size_t)NB * CAP + 64) * 4);  // ~8 MB; becomes csr in-place
    __half*   ht1  = (__half*)alloc((size_t)n * HID * 2);     // fp16 gather table
    float*    h1p  = (float*)alloc((size_t)n * HID * 4);
    __half*   ht2  = ht1;  // ht1 dead after agg1; reuse region

    hipMemsetAsync(gcursor, 0, (size_t)NB * 4, stream);

    int nch = (E + CH - 1) / CH;  // 196
    partition_kernel<<<nch, 1024, 0, stream>>>(srcv, dstv, E, gcursor, ebuf);
    localsort_kernel<<<NB, 256, 0, stream>>>(ebuf, gcursor, ns, ne, dinv, n);
    constprep_kernel<<<1, 64, 0, stream>>>(g1, be1, rm1, rv1, b1, g2, be2, rm2, rv2, b2, A1, B1, A2, B2);

    int g1blocks = 512;           // 2048 waves
    gemm1_kernel<<<g1blocks, 256, 0, stream>>>(x, W1, dinv, ht1, n, g1blocks * 4);
    agg1_kernel<<<(n + 3) / 4, 256, 0, stream>>>(ht1, ns, ne, (const int*)ebuf, dinv, A1, B1, h1p, n);
    int ngb = (n + 63) / 64;      // 1563
    gemm2_kernel<<<ngb, 256, 0, stream>>>(h1p, W2, dinv, ht2, n);
    agg2_kernel<<<(n + 3) / 4, 256, 0, stream>>>(ht2, ns, ne, (const int*)ebuf, dinv, A2, B2, Wc, bc, out, n);
}